// Round 15
// baseline (159.663 us; speedup 1.0000x reference)
//
#include <hip/hip_runtime.h>
#include <cmath>

// GAT layer: N=4096 nodes, FIN=128, F=64 per head, H=8 heads.
//   v15 = v14 front-end (K1: swizzle||A-pack-lo, K2: feats||A-pack-hi)
//   + attn with ET/ETN/bits moved from LDS staging to per-wave REGISTER
//   prefetch from global (L2-hot, no cross-wave sharing -> LDS staging
//   of them paid DMA+ds_read for nothing). Cuts wave-step LDS reads by
//   ~1/3 (removes 2 b128 + 2 b64); stage = feats-only (uniform 2
//   gloads/wave -> clean vmcnt(2) every iter). B-frags stay LDS-staged
//   (2-way shared; streaming them cost ~5us in v0-v5). Parity (A/B)
//   register sets avoid copies; x6 unroll keeps slot indices (x3) and
//   parity (x2) compile-time. LB(512,4): ~115 regs < 128 cap (acc kept
//   at rt=2's 40 regs -- v12's spill mode checked).

#define NN 4096
#define FIN 128
#define FF 64
#define HH 8

typedef _Float16 h2 __attribute__((ext_vector_type(2)));
typedef _Float16 h4 __attribute__((ext_vector_type(4)));
typedef _Float16 h8 __attribute__((ext_vector_type(8)));
typedef float f32x2 __attribute__((ext_vector_type(2)));
typedef float f32x4 __attribute__((ext_vector_type(4)));

union H8 {
  h8 v;
  h2 p[4];
};
union H4 {
  h4 v;
  h2 p[2];
};

// async global->LDS, 16B per lane (dest = wave-uniform base + lane*16)
static __device__ __forceinline__ void gload16(const void* g, void* l) {
  __builtin_amdgcn_global_load_lds(
      (const __attribute__((address_space(1))) unsigned int*)g,
      (__attribute__((address_space(3))) unsigned int*)l, 16, 0, 0);
}

// ---------------------------------------------------------------- helpers
// pack one A-row (256 thr): int4 loads + per-wave LDS transpose + ballot.
static __device__ __forceinline__ void pack_row(const int* __restrict__ A,
                                                unsigned long long* __restrict__
                                                    bits,
                                                int row, int tid) {
  __shared__ int ldsT[4][4][256];  // [wave][iter][col-within-group]
  const int wave = tid >> 6, lane = tid & 63;
  const int* ar = A + (size_t)row * NN;
  int4 v[4];
#pragma unroll
  for (int it = 0; it < 4; ++it) {
    const int g = wave * 4 + it;  // 256-col group
    v[it] = *(const int4*)(ar + g * 256 + lane * 4);
  }
#pragma unroll
  for (int it = 0; it < 4; ++it) *(int4*)&ldsT[wave][it][lane * 4] = v[it];
  unsigned long long* br = bits + ((size_t)row << 6);
#pragma unroll
  for (int it = 0; it < 4; ++it) {
    const int g = wave * 4 + it;
    int w0 = ldsT[wave][it][0 * 64 + lane];
    int w1 = ldsT[wave][it][1 * 64 + lane];
    int w2 = ldsT[wave][it][2 * 64 + lane];
    int w3 = ldsT[wave][it][3 * 64 + lane];
    unsigned long long m0 = __ballot(w0 != 0);
    unsigned long long m1 = __ballot(w1 != 0);
    unsigned long long m2 = __ballot(w2 != 0);
    unsigned long long m3 = __ballot(w3 != 0);
    if (lane == 0) {
      ulonglong2 p0 = {m0, m1}, p1 = {m2, m3};
      *(ulonglong2*)(br + g * 4 + 0) = p0;
      *(ulonglong2*)(br + g * 4 + 2) = p1;
    }
  }
}

// ---------------------------------------------------------------- kernel K1
// blocks [0,2): W -> f16 MFMA-B-frag order (4 heads each).
// blocks [2,66): X -> f16 MFMA-A-frag order (4 row-tiles each).
// blocks [66,66+2048): pack A rows 0..2047.
__global__ __launch_bounds__(256) void k1_kernel(
    const int* __restrict__ A, const float* __restrict__ W,
    const float* __restrict__ X, unsigned long long* __restrict__ bits,
    _Float16* __restrict__ Wsw, _Float16* __restrict__ Xsw) {
  const int b = blockIdx.x;
  const int tid = threadIdx.x;
  const int wave = tid >> 6, lane = tid & 63;
  if (b < 2) {
    const int h0 = b * 4;
    for (int h = h0; h < h0 + 4; ++h) {
      for (int c = tid; c < 1024; c += 256) {  // (kt, nb, lane)
        int ln = c & 63, nb = (c >> 6) & 3, kt = c >> 8;
        int f = nb * 16 + (ln & 15);
        int k0 = kt * 32 + (ln >> 4) * 8;
        h8 v;
#pragma unroll
        for (int j = 0; j < 8; ++j)
          v[j] = (_Float16)W[((size_t)(h * FIN) + k0 + j) * FF + f];
        *(h8*)(Wsw + ((size_t)(((h * 4 + kt) * 4 + nb) * 64 + ln)) * 8) = v;
      }
    }
  } else if (b < 66) {
    const int tile = (b - 2) * 4 + wave;  // 16-row tile, 0..255
    const int l16 = lane & 15, quad = lane >> 4;
    const float* xr = X + (size_t)(tile * 16 + l16) * FIN;
#pragma unroll
    for (int kt = 0; kt < 4; ++kt) {
      int k0 = kt * 32 + quad * 8;
      f32x4 x0 = *(const f32x4*)(xr + k0);
      f32x4 x1 = *(const f32x4*)(xr + k0 + 4);
      h8 v = {(_Float16)x0[0], (_Float16)x0[1], (_Float16)x0[2],
              (_Float16)x0[3], (_Float16)x1[0], (_Float16)x1[1],
              (_Float16)x1[2], (_Float16)x1[3]};
      *(h8*)(Xsw + ((size_t)((tile * 4 + kt) * 64 + lane)) * 8) = v;
    }
  } else {
    pack_row(A, bits, b - 66, tid);
  }
}

// ---------------------------------------------------------------- kernel K2
// blocks [0,512): feats for (rb = b&63, h = b>>6) — dispatched first.
// blocks [512,512+2048): pack A rows 2048..4095.
__global__ __launch_bounds__(256) void k2_kernel(
    const int* __restrict__ A, unsigned long long* __restrict__ bits,
    const _Float16* __restrict__ Xsw, const _Float16* __restrict__ Wsw,
    const float* __restrict__ a_self, const float* __restrict__ a_neigh,
    _Float16* __restrict__ feats_sw, _Float16* __restrict__ es_h,
    _Float16* __restrict__ esn_h, _Float16* __restrict__ et_h,
    _Float16* __restrict__ etn_h) {
  const int b = blockIdx.x;
  const int tid = threadIdx.x, wave = tid >> 6, lane = tid & 63;
  if (b >= 512) {
    pack_row(A, bits, 2048 + (b - 512), tid);
    return;
  }
  const int rb = b & 63, h = b >> 6;
  const int l16 = lane & 15, quad = lane >> 4;
  const int rt = rb * 4 + wave;  // 16-row tile
  const int r0 = rt * 16;

  f32x4 acc[4];
#pragma unroll
  for (int nb = 0; nb < 4; ++nb) acc[nb] = (f32x4){0.f, 0.f, 0.f, 0.f};

  const _Float16* xp = Xsw + ((size_t)(rt * 4) * 64 + lane) * 8;
  const _Float16* wp = Wsw + ((size_t)(h * 16) * 64 + lane) * 8;
  h8 Af[4];
#pragma unroll
  for (int kt = 0; kt < 4; ++kt) Af[kt] = *(const h8*)(xp + kt * 512);
#pragma unroll
  for (int kt = 0; kt < 4; ++kt)
#pragma unroll
    for (int nb = 0; nb < 4; ++nb) {
      h8 Bf = *(const h8*)(wp + (kt * 4 + nb) * 512);
      acc[nb] = __builtin_amdgcn_mfma_f32_16x16x32_f16(Af[kt], Bf, acc[nb], 0, 0, 0);
    }

  // s_self/s_neigh dots (fp32) -> factored exponentials (f16)
  float as[4], an[4];
#pragma unroll
  for (int nb = 0; nb < 4; ++nb) {
    as[nb] = a_self[h * FF + nb * 16 + l16];
    an[nb] = a_neigh[h * FF + nb * 16 + l16];
  }
#pragma unroll
  for (int r = 0; r < 4; ++r) {
    float ps = acc[0][r] * as[0] + acc[1][r] * as[1] + acc[2][r] * as[2] +
               acc[3][r] * as[3];
    float pn = acc[0][r] * an[0] + acc[1][r] * an[1] + acc[2][r] * an[2] +
               acc[3][r] * an[3];
#pragma unroll
    for (int m = 1; m <= 8; m <<= 1) {
      ps += __shfl_xor(ps, m, 64);
      pn += __shfl_xor(pn, m, 64);
    }
    if (l16 == 0) {
      int node = h * NN + r0 + quad * 4 + r;
      es_h[node] = (_Float16)__expf(ps - 2.0f);
      esn_h[node] = (_Float16)__expf(0.2f * ps - 2.0f);
      et_h[node] = (_Float16)__expf(pn - 2.0f);
      etn_h[node] = (_Float16)__expf(0.2f * pn - 2.0f);
    }
  }

  // swizzled f16 store (MFMA B-fragment order). node = r0 + quad*4 + r.
  const int kb = r0 >> 5;
  const int quadA = ((r0 >> 4) & 1) * 2 + (quad >> 1);
  const int jbase = (quad & 1) << 2;
#pragma unroll
  for (int nb = 0; nb < 4; ++nb) {
    h4 v = {(_Float16)acc[nb][0], (_Float16)acc[nb][1], (_Float16)acc[nb][2],
            (_Float16)acc[nb][3]};
    size_t off = ((size_t)((h * 128 + kb) * 4 + nb) << 9) +
                 ((quadA * 16 + l16) << 3) + jbase;
    *(h4*)(feats_sw + off) = v;
  }
}

// ---------------------------------------------------------------- kernel 2
// grid 512 = rb*8 + h (head -> XCD). 64 rows/block, 512 thr = 8 waves:
// wave = kfw*4 + ctw*2 + rh; computes (ct=2s+ctw, kf=kfw) for the 32
// rows of half rh. B-frags LDS-staged (feats-only slots, 3-buf rotation,
// uniform vmcnt(2), stage-after-barrier); ET/ETN/bits prefetched one
// step ahead into parity register sets (A/B). Den via mfma(P, ones).
// LUT masks; setprio around MFMA clusters; x6 unroll (slot + parity
// compile-time). LDS 48KB + LUT -> 2 blocks/CU -> 4 waves/SIMD.
__global__ __launch_bounds__(512, 4) void attn_kernel(
    const unsigned long long* __restrict__ Abits,
    const _Float16* __restrict__ feats_sw, const _Float16* __restrict__ es_h,
    const _Float16* __restrict__ esn_h, const _Float16* __restrict__ et_h,
    const _Float16* __restrict__ etn_h, const float* __restrict__ bias,
    float* __restrict__ out) {
  const int bid = blockIdx.x;
  const int h = bid & 7, n0 = (bid >> 3) << 6;  // 64 rows per block
  const int tid = threadIdx.x, wave = tid >> 6, lane = tid & 63;
  const int l16 = lane & 15, quad = lane >> 4;
  const int rh = wave & 1, ctw = (wave >> 1) & 1, kfw = wave >> 2;
  const int shTot = (kfw << 5) + (quad << 3);  // 64-bit shift amount

  __shared__ __align__(16) char smem[3 * 16384];  // 48 KB (feats slots)
  __shared__ h4 lutS[16];                         // 128 B = 32 banks

  // nibble -> 4 f16 {0,1} masks
  if (tid < 16) {
    h4 m;
#pragma unroll
    for (int j = 0; j < 4; ++j) m[j] = (_Float16)((tid >> j) & 1);
    lutS[tid] = m;
  }
  __syncthreads();

  // per-row self exponentials for my 2 row-tiles (rows rh*32 + rt*16 + l16)
  h2 esp[2], esnp[2];
#pragma unroll
  for (int rt = 0; rt < 2; ++rt) {
    const int myrow = n0 + (rh << 5) + (rt << 4) + l16;
    _Float16 e = es_h[h * NN + myrow];
    _Float16 en = esn_h[h * NN + myrow];
    esp[rt] = (h2){e, e};
    esnp[rt] = (h2){en, en};
  }

  f32x4 acc[2][4], accd[2];
#pragma unroll
  for (int rt = 0; rt < 2; ++rt) {
    accd[rt] = (f32x4){0.f, 0.f, 0.f, 0.f};
#pragma unroll
    for (int nb = 0; nb < 4; ++nb) acc[rt][nb] = (f32x4){0.f, 0.f, 0.f, 0.f};
  }
  const h8 ONES = {(_Float16)1.f, (_Float16)1.f, (_Float16)1.f, (_Float16)1.f,
                   (_Float16)1.f, (_Float16)1.f, (_Float16)1.f, (_Float16)1.f};

  // global bases
  const char* gF = (const char*)feats_sw + ((size_t)h << 19);  // h*512KB
  const char* gE = (const char*)et_h + (h << 13);
  const char* gEN = (const char*)etn_h + (h << 13);
  const char* gB = (const char*)Abits + ((size_t)n0 << 9);

  // per-wave register-prefetch offsets (ct = 2s+ctw)
  const unsigned eOff = (ctw << 7) + (kfw << 6) + (quad << 4);  // + s*256
  const unsigned bOff0 = (((rh << 5) + l16) << 9) + (ctw << 3);  // + s*16
  const unsigned bOff1 = bOff0 + 8192;                           // +16 rows

  // parity register sets
  H8 ETa, ETNa, ETb, ETNb;
  unsigned long long mba0, mba1, mbb0, mbb1;

#define PREF(s_, ET_, ETN_, M0_, M1_)                                          \
  do {                                                                         \
    ET_.v = *(const h8*)(gE + ((s_) << 8) + eOff);                             \
    ETN_.v = *(const h8*)(gEN + ((s_) << 8) + eOff);                           \
    M0_ = *(const unsigned long long*)(gB + bOff0 + ((s_) << 4));              \
    M1_ = *(const unsigned long long*)(gB + bOff1 + ((s_) << 4));              \
  } while (0)

  // stage step s (cts 2s, 2s+1): feats 16KB, 2 gloads per wave (uniform)
#define STAGE(s_, SLOT_)                                                       \
  do {                                                                         \
    char* L_ = smem + (SLOT_)*16384;                                           \
    const char* src_ = gF + ((size_t)(s_) << 14) + (wave << 11) + (lane << 4); \
    gload16(src_, L_ + (wave << 11) + (lane << 4));                            \
    gload16(src_ + 1024, L_ + (wave << 11) + 1024 + (lane << 4));              \
  } while (0)

// one step: compile-time slot SL/NSL; ETu/M* = current set; ETn/Mn* = next
#define ITER(s_, SL, NSL, ETu, ETNu, M0u, M1u, ETn, ETNn, M0n, M1n, dopref_,   \
             dostage_, last_)                                                  \
  {                                                                            \
    __builtin_amdgcn_sched_barrier(0);                                         \
    if (last_) {                                                               \
      asm volatile("s_waitcnt vmcnt(0)" ::: "memory");                         \
    } else {                                                                   \
      asm volatile("s_waitcnt vmcnt(2)" ::: "memory");                         \
    }                                                                          \
    __builtin_amdgcn_sched_barrier(0);                                         \
    __builtin_amdgcn_s_barrier();                                              \
    if (dopref_) PREF((s_) + 1, ETn, ETNn, M0n, M1n);                          \
    if (dostage_) STAGE((s_) + 2, NSL);                                        \
    __builtin_amdgcn_sched_barrier(0);                                         \
    const char* L = smem + (SL)*16384;                                         \
    const char* fB = L + (ctw << 13) + (kfw << 12) + (lane << 4);              \
    h8 B0 = *(const h8*)(fB);                                                  \
    h8 B1 = *(const h8*)(fB + 1024);                                           \
    h8 B2 = *(const h8*)(fB + 2048);                                           \
    h8 B3 = *(const h8*)(fB + 3072);                                           \
    _Pragma("unroll") for (int rt = 0; rt < 2; ++rt) {                         \
      const unsigned byt = (unsigned)(((rt ? M1u : M0u) >> shTot)) & 0xFFu;    \
      H4 mlo, mhi;                                                             \
      mlo.v = lutS[byt & 15u];                                                 \
      mhi.v = lutS[byt >> 4];                                                  \
      H8 P;                                                                    \
      _Pragma("unroll") for (int p = 0; p < 4; ++p) {                          \
        h2 a_ = esp[rt] * ETu.p[p];                                            \
        h2 b_ = esnp[rt] * ETNu.p[p];                                          \
        h2 r_ = __builtin_elementwise_max(a_, b_);                             \
        P.p[p] = r_ * (p < 2 ? mlo.p[p] : mhi.p[p - 2]);                       \
      }                                                                        \
      __builtin_amdgcn_s_setprio(1);                                           \
      acc[rt][0] =                                                             \
          __builtin_amdgcn_mfma_f32_16x16x32_f16(P.v, B0, acc[rt][0], 0, 0, 0);\
      acc[rt][1] =                                                             \
          __builtin_amdgcn_mfma_f32_16x16x32_f16(P.v, B1, acc[rt][1], 0, 0, 0);\
      acc[rt][2] =                                                             \
          __builtin_amdgcn_mfma_f32_16x16x32_f16(P.v, B2, acc[rt][2], 0, 0, 0);\
      acc[rt][3] =                                                             \
          __builtin_amdgcn_mfma_f32_16x16x32_f16(P.v, B3, acc[rt][3], 0, 0, 0);\
      accd[rt] =                                                               \
          __builtin_amdgcn_mfma_f32_16x16x32_f16(P.v, ONES, accd[rt], 0, 0, 0);\
      __builtin_amdgcn_s_setprio(0);                                           \
    }                                                                          \
  }

#define ITER_A(s_, SL, NSL, dopref_, dostage_, last_)                          \
  ITER(s_, SL, NSL, ETa, ETNa, mba0, mba1, ETb, ETNb, mbb0, mbb1, dopref_,     \
       dostage_, last_)
#define ITER_B(s_, SL, NSL, dopref_, dostage_, last_)                          \
  ITER(s_, SL, NSL, ETb, ETNb, mbb0, mbb1, ETa, ETNa, mba0, mba1, dopref_,     \
       dostage_, last_)

  // prologue: queue (old->new) = [pref(0) 4, stage(0) 2, stage(1) 2]
  PREF(0, ETa, ETNa, mba0, mba1);
  STAGE(0, 0);
  STAGE(1, 1);

  for (int sb = 0; sb < 30; sb += 6) {
    ITER_A(sb + 0, 0, 2, 1, 1, 0);
    ITER_B(sb + 1, 1, 0, 1, 1, 0);
    ITER_A(sb + 2, 2, 1, 1, 1, 0);
    ITER_B(sb + 3, 0, 2, 1, 1, 0);
    ITER_A(sb + 4, 1, 0, 1, 1, 0);
    ITER_B(sb + 5, 2, 1, 1, 1, 0);
  }
  ITER_A(30, 0, 2, 1, 0, 0);  // pref(31) into B, no stage
  ITER_B(31, 1, 0, 0, 0, 1);  // vmcnt(0)
#undef ITER_A
#undef ITER_B
#undef ITER
#undef STAGE
#undef PREF

  // epilogue: 2 phases (rt); 4-way cross-wave reduce via re-used LDS.
  // accd[rt][r]: every lane holds den(row quad*4+r).
  float(*accL)[16][68] = (float(*)[16][68])smem;   // 34,816 B
  float* denL = (float*)(smem + 8 * 16 * 68 * 4);  // 512 B
  const int erow = tid >> 4;  // 0..31
  const int rh_o = erow >> 4, r16 = erow & 15;
  const int ec0 = (tid & 15) << 2;
#pragma unroll
  for (int rt = 0; rt < 2; ++rt) {
    __syncthreads();
#pragma unroll
    for (int nb = 0; nb < 4; ++nb)
#pragma unroll
      for (int r = 0; r < 4; ++r)
        accL[wave][quad * 4 + r][nb * 16 + l16] = acc[rt][nb][r];
    if (l16 == 0) {
#pragma unroll
      for (int r = 0; r < 4; ++r) denL[wave * 16 + quad * 4 + r] = accd[rt][r];
    }
    __syncthreads();
    f32x4 v = (f32x4){0.f, 0.f, 0.f, 0.f};
    float dn = 0.f;
#pragma unroll
    for (int cw = 0; cw < 4; ++cw) {
      const int w = rh_o + ((cw & 1) << 1) + ((cw >> 1) << 2);
      v += *(const f32x4*)&accL[w][r16][ec0];
      dn += denL[w * 16 + r16];
    }
    float inv = 1.0f / dn;  // self loop -> dn > 0
    const f32x4 bv = *(const f32x4*)(bias + h * FF + ec0);
#pragma unroll
    for (int i = 0; i < 4; ++i) {
      float x = v[i] * inv + bv[i];
      v[i] = x > 0.f ? x : (__expf(x) - 1.0f);
    }
    *(f32x4*)(out + (size_t)(n0 + (rh_o << 5) + (rt << 4) + r16) * (HH * FF) +
              h * FF + ec0) = v;
  }
}

// ---------------------------------------------------------------- launch
extern "C" void kernel_launch(void* const* d_in, const int* in_sizes, int n_in,
                              void* d_out, int out_size, void* d_ws,
                              size_t ws_size, hipStream_t stream) {
  const float* X = (const float*)d_in[0];
  const int* A = (const int*)d_in[1];
  const float* W = (const float*)d_in[2];
  const float* b = (const float*)d_in[3];
  const float* a_self = (const float*)d_in[4];
  const float* a_neigh = (const float*)d_in[5];
  float* out = (float*)d_out;

  char* ws = (char*)d_ws;
  unsigned long long* Abits = (unsigned long long*)ws;        // 2 MB
  _Float16* feats_sw = (_Float16*)(ws + (2u << 20));          // 4 MB
  _Float16* es_h = (_Float16*)(ws + (6u << 20));              // 64 KB each
  _Float16* esn_h = (_Float16*)(ws + (6u << 20) + (64u << 10));
  _Float16* et_h = (_Float16*)(ws + (6u << 20) + (128u << 10));
  _Float16* etn_h = (_Float16*)(ws + (6u << 20) + (192u << 10));
  _Float16* Wsw = (_Float16*)(ws + (6u << 20) + (256u << 10));   // 128 KB
  _Float16* Xsw = (_Float16*)(ws + (6u << 20) + (384u << 10));   // 1 MB

  // K1: swizzle (66) || A-pack rows 0..2047 (2048)
  k1_kernel<<<66 + 2048, 256, 0, stream>>>(A, W, X, Abits, Wsw, Xsw);
  // K2: feats (512, first) || A-pack rows 2048..4095 (2048)
  k2_kernel<<<512 + 2048, 256, 0, stream>>>(A, Abits, Xsw, Wsw, a_self,
                                            a_neigh, feats_sw, es_h, esn_h,
                                            et_h, etn_h);
  // K3: attn
  attn_kernel<<<512, 512, 0, stream>>>(Abits, feats_sw, es_h, esn_h, et_h,
                                       etn_h, b, out);
}

// Round 17
// 140.505 us; speedup vs baseline: 1.1363x; 1.1363x over previous
//
#include <hip/hip_runtime.h>
#include <cmath>

// GAT layer: N=4096 nodes, FIN=128, F=64 per head, H=8 heads.
//   v16 = v14 VERBATIM (session best, 141.75us; round-16 run was an
//   infra failure, resubmitting). Ledger: attn (~39us) probed on every
//   axis across 15 variants (latency/TLP/bank-conf/LDS-BW/barriers/
//   VALU/multiplicity/reg-prefetch) -> dependency-serialization plateau
//   of the stage->barrier->ds_read->P->MFMA structure. Front-end ~15us
//   = A-read HBM floor. Fills ~84us harness-fixed.
//   K1: swizzle (66 blocks) || A-pack rows 0..2047
//   K2: feats (512 blocks, first) || A-pack rows 2048..4095
//   K3: attn v11 (rt=2, 4 waves/SIMD, 3-slot counted-vmcnt, LUT masks,
//       x3 unroll, setprio, MFMA-ones denominator)

#define NN 4096
#define FIN 128
#define FF 64
#define HH 8

typedef _Float16 h2 __attribute__((ext_vector_type(2)));
typedef _Float16 h4 __attribute__((ext_vector_type(4)));
typedef _Float16 h8 __attribute__((ext_vector_type(8)));
typedef float f32x2 __attribute__((ext_vector_type(2)));
typedef float f32x4 __attribute__((ext_vector_type(4)));

union H8 {
  h8 v;
  h2 p[4];
};
union H4 {
  h4 v;
  h2 p[2];
};

static __device__ __forceinline__ float dot2acc(h2 a, float c) {
#if __has_builtin(__builtin_amdgcn_fdot2)
  return __builtin_amdgcn_fdot2(a, (h2){(_Float16)1.f, (_Float16)1.f}, c,
                                false);
#else
  return c + (float)a[0] + (float)a[1];
#endif
}

// async global->LDS, 16B per lane (dest = wave-uniform base + lane*16)
static __device__ __forceinline__ void gload16(const void* g, void* l) {
  __builtin_amdgcn_global_load_lds(
      (const __attribute__((address_space(1))) unsigned int*)g,
      (__attribute__((address_space(3))) unsigned int*)l, 16, 0, 0);
}

// ---------------------------------------------------------------- helpers
// pack one A-row (256 thr): int4 loads + per-wave LDS transpose + ballot.
static __device__ __forceinline__ void pack_row(const int* __restrict__ A,
                                                unsigned long long* __restrict__
                                                    bits,
                                                int row, int tid) {
  __shared__ int ldsT[4][4][256];  // [wave][iter][col-within-group]
  const int wave = tid >> 6, lane = tid & 63;
  const int* ar = A + (size_t)row * NN;
  int4 v[4];
#pragma unroll
  for (int it = 0; it < 4; ++it) {
    const int g = wave * 4 + it;  // 256-col group
    v[it] = *(const int4*)(ar + g * 256 + lane * 4);
  }
#pragma unroll
  for (int it = 0; it < 4; ++it) *(int4*)&ldsT[wave][it][lane * 4] = v[it];
  unsigned long long* br = bits + ((size_t)row << 6);
#pragma unroll
  for (int it = 0; it < 4; ++it) {
    const int g = wave * 4 + it;
    int w0 = ldsT[wave][it][0 * 64 + lane];
    int w1 = ldsT[wave][it][1 * 64 + lane];
    int w2 = ldsT[wave][it][2 * 64 + lane];
    int w3 = ldsT[wave][it][3 * 64 + lane];
    unsigned long long m0 = __ballot(w0 != 0);
    unsigned long long m1 = __ballot(w1 != 0);
    unsigned long long m2 = __ballot(w2 != 0);
    unsigned long long m3 = __ballot(w3 != 0);
    if (lane == 0) {
      ulonglong2 p0 = {m0, m1}, p1 = {m2, m3};
      *(ulonglong2*)(br + g * 4 + 0) = p0;
      *(ulonglong2*)(br + g * 4 + 2) = p1;
    }
  }
}

// ---------------------------------------------------------------- kernel K1
// blocks [0,2): W -> f16 MFMA-B-frag order (4 heads each).
// blocks [2,66): X -> f16 MFMA-A-frag order (4 row-tiles each).
// blocks [66,66+2048): pack A rows 0..2047.
__global__ __launch_bounds__(256) void k1_kernel(
    const int* __restrict__ A, const float* __restrict__ W,
    const float* __restrict__ X, unsigned long long* __restrict__ bits,
    _Float16* __restrict__ Wsw, _Float16* __restrict__ Xsw) {
  const int b = blockIdx.x;
  const int tid = threadIdx.x;
  const int wave = tid >> 6, lane = tid & 63;
  if (b < 2) {
    const int h0 = b * 4;
    for (int h = h0; h < h0 + 4; ++h) {
      for (int c = tid; c < 1024; c += 256) {  // (kt, nb, lane)
        int ln = c & 63, nb = (c >> 6) & 3, kt = c >> 8;
        int f = nb * 16 + (ln & 15);
        int k0 = kt * 32 + (ln >> 4) * 8;
        h8 v;
#pragma unroll
        for (int j = 0; j < 8; ++j)
          v[j] = (_Float16)W[((size_t)(h * FIN) + k0 + j) * FF + f];
        *(h8*)(Wsw + ((size_t)(((h * 4 + kt) * 4 + nb) * 64 + ln)) * 8) = v;
      }
    }
  } else if (b < 66) {
    const int tile = (b - 2) * 4 + wave;  // 16-row tile, 0..255
    const int l16 = lane & 15, quad = lane >> 4;
    const float* xr = X + (size_t)(tile * 16 + l16) * FIN;
#pragma unroll
    for (int kt = 0; kt < 4; ++kt) {
      int k0 = kt * 32 + quad * 8;
      f32x4 x0 = *(const f32x4*)(xr + k0);
      f32x4 x1 = *(const f32x4*)(xr + k0 + 4);
      h8 v = {(_Float16)x0[0], (_Float16)x0[1], (_Float16)x0[2],
              (_Float16)x0[3], (_Float16)x1[0], (_Float16)x1[1],
              (_Float16)x1[2], (_Float16)x1[3]};
      *(h8*)(Xsw + ((size_t)((tile * 4 + kt) * 64 + lane)) * 8) = v;
    }
  } else {
    pack_row(A, bits, b - 66, tid);
  }
}

// ---------------------------------------------------------------- kernel K2
// blocks [0,512): feats for (rb = b&63, h = b>>6) — dispatched first.
// blocks [512,512+2048): pack A rows 2048..4095.
__global__ __launch_bounds__(256) void k2_kernel(
    const int* __restrict__ A, unsigned long long* __restrict__ bits,
    const _Float16* __restrict__ Xsw, const _Float16* __restrict__ Wsw,
    const float* __restrict__ a_self, const float* __restrict__ a_neigh,
    _Float16* __restrict__ feats_sw, _Float16* __restrict__ es_h,
    _Float16* __restrict__ esn_h, _Float16* __restrict__ et_h,
    _Float16* __restrict__ etn_h) {
  const int b = blockIdx.x;
  const int tid = threadIdx.x, wave = tid >> 6, lane = tid & 63;
  if (b >= 512) {
    pack_row(A, bits, 2048 + (b - 512), tid);
    return;
  }
  const int rb = b & 63, h = b >> 6;
  const int l16 = lane & 15, quad = lane >> 4;
  const int rt = rb * 4 + wave;  // 16-row tile
  const int r0 = rt * 16;

  f32x4 acc[4];
#pragma unroll
  for (int nb = 0; nb < 4; ++nb) acc[nb] = (f32x4){0.f, 0.f, 0.f, 0.f};

  const _Float16* xp = Xsw + ((size_t)(rt * 4) * 64 + lane) * 8;
  const _Float16* wp = Wsw + ((size_t)(h * 16) * 64 + lane) * 8;
  h8 Af[4];
#pragma unroll
  for (int kt = 0; kt < 4; ++kt) Af[kt] = *(const h8*)(xp + kt * 512);
#pragma unroll
  for (int kt = 0; kt < 4; ++kt)
#pragma unroll
    for (int nb = 0; nb < 4; ++nb) {
      h8 Bf = *(const h8*)(wp + (kt * 4 + nb) * 512);
      acc[nb] = __builtin_amdgcn_mfma_f32_16x16x32_f16(Af[kt], Bf, acc[nb], 0, 0, 0);
    }

  // s_self/s_neigh dots (fp32) -> factored exponentials (f16)
  float as[4], an[4];
#pragma unroll
  for (int nb = 0; nb < 4; ++nb) {
    as[nb] = a_self[h * FF + nb * 16 + l16];
    an[nb] = a_neigh[h * FF + nb * 16 + l16];
  }
#pragma unroll
  for (int r = 0; r < 4; ++r) {
    float ps = acc[0][r] * as[0] + acc[1][r] * as[1] + acc[2][r] * as[2] +
               acc[3][r] * as[3];
    float pn = acc[0][r] * an[0] + acc[1][r] * an[1] + acc[2][r] * an[2] +
               acc[3][r] * an[3];
#pragma unroll
    for (int m = 1; m <= 8; m <<= 1) {
      ps += __shfl_xor(ps, m, 64);
      pn += __shfl_xor(pn, m, 64);
    }
    if (l16 == 0) {
      int node = h * NN + r0 + quad * 4 + r;
      es_h[node] = (_Float16)__expf(ps - 2.0f);
      esn_h[node] = (_Float16)__expf(0.2f * ps - 2.0f);
      et_h[node] = (_Float16)__expf(pn - 2.0f);
      etn_h[node] = (_Float16)__expf(0.2f * pn - 2.0f);
    }
  }

  // swizzled f16 store (MFMA B-fragment order). node = r0 + quad*4 + r.
  const int kb = r0 >> 5;
  const int quadA = ((r0 >> 4) & 1) * 2 + (quad >> 1);
  const int jbase = (quad & 1) << 2;
#pragma unroll
  for (int nb = 0; nb < 4; ++nb) {
    h4 v = {(_Float16)acc[nb][0], (_Float16)acc[nb][1], (_Float16)acc[nb][2],
            (_Float16)acc[nb][3]};
    size_t off = ((size_t)((h * 128 + kb) * 4 + nb) << 9) +
                 ((quadA * 16 + l16) << 3) + jbase;
    *(h4*)(feats_sw + off) = v;
  }
}

// ---------------------------------------------------------------- kernel 2
// v11 VERBATIM. grid 512 = rb*8 + h (head -> XCD). 64 rows/block, 512
// thr = 8 waves: wave = kfw*4 + ctw*2 + rh; wave computes (ct=2s+ctw,
// kf=kfw) for the 32 rows of half rh. Denominator via mfma(P, ones).
// Stage-after-barrier 3-buf rotation, counted vmcnt(3|2). Loop unrolled
// x3: slot index compile-time -> ds offsets immediate. Masks via
// 16-entry h4 LDS LUT. setprio(1) around MFMA clusters. LDS 58.4KB+LUT
// -> 2 blocks/CU -> 4 waves/SIMD.
__global__ __launch_bounds__(512, 4) void attn_kernel(
    const unsigned long long* __restrict__ Abits,
    const _Float16* __restrict__ feats_sw, const _Float16* __restrict__ es_h,
    const _Float16* __restrict__ esn_h, const _Float16* __restrict__ et_h,
    const _Float16* __restrict__ etn_h, const float* __restrict__ bias,
    float* __restrict__ out) {
  const int bid = blockIdx.x;
  const int h = bid & 7, n0 = (bid >> 3) << 6;  // 64 rows per block
  const int tid = threadIdx.x, wave = tid >> 6, lane = tid & 63;
  const int l16 = lane & 15, quad = lane >> 4;
  const int rh = wave & 1, ctw = (wave >> 1) & 1, kfw = wave >> 2;
  const int shTot = (kfw << 5) + (quad << 3);  // 64-bit shift amount

  __shared__ __align__(16) char smem[3 * 19456];  // 58.4 KB
  __shared__ h4 lutS[16];                         // 128 B = 32 banks

  // nibble -> 4 f16 {0,1} masks
  if (tid < 16) {
    h4 m;
#pragma unroll
    for (int j = 0; j < 4; ++j) m[j] = (_Float16)((tid >> j) & 1);
    lutS[tid] = m;
  }
  __syncthreads();

  // per-row self exponentials for my 2 row-tiles (rows rh*32 + rt*16 + l16)
  h2 esp[2], esnp[2];
#pragma unroll
  for (int rt = 0; rt < 2; ++rt) {
    const int myrow = n0 + (rh << 5) + (rt << 4) + l16;
    _Float16 e = es_h[h * NN + myrow];
    _Float16 en = esn_h[h * NN + myrow];
    esp[rt] = (h2){e, e};
    esnp[rt] = (h2){en, en};
  }

  f32x4 acc[2][4], accd[2];
#pragma unroll
  for (int rt = 0; rt < 2; ++rt) {
    accd[rt] = (f32x4){0.f, 0.f, 0.f, 0.f};
#pragma unroll
    for (int nb = 0; nb < 4; ++nb) acc[rt][nb] = (f32x4){0.f, 0.f, 0.f, 0.f};
  }
  const h8 ONES = {(_Float16)1.f, (_Float16)1.f, (_Float16)1.f, (_Float16)1.f,
                   (_Float16)1.f, (_Float16)1.f, (_Float16)1.f, (_Float16)1.f};

  // global bases
  const char* gF = (const char*)feats_sw + ((size_t)h << 19);  // h*512KB
  const char* gE = (const char*)et_h + (h << 13);
  const char* gEN = (const char*)etn_h + (h << 13);
  const char* gB = (const char*)Abits + ((size_t)n0 << 9);

#define STAGE(s_, Lp_)                                                         \
  do {                                                                         \
    char* L_ = (char*)(Lp_);                                                   \
    const char* src_ = gF + ((size_t)(s_) << 14) + (wave << 11) + (lane << 4); \
    gload16(src_, L_ + (wave << 11) + (lane << 4));                            \
    gload16(src_ + 1024, L_ + (wave << 11) + 1024 + (lane << 4));              \
    if (wave == 0)                                                             \
      gload16(gE + ((s_) << 8) + (l16 << 4), L_ + 16384 + (lane << 4));        \
    if (wave == 1)                                                             \
      gload16(gEN + ((s_) << 8) + (l16 << 4), L_ + 17408 + (lane << 4));       \
    if (wave == 2)                                                             \
      gload16(gB + ((size_t)lane << 9) + ((s_) << 4), L_ + 18432 + (lane << 4)); \
  } while (0)

// one step: slot SL (compile-time), stage (s_+2) into slot NSL if dostage_
#define ITER(s_, SL, NSL, dostage_, last_)                                     \
  {                                                                            \
    __builtin_amdgcn_sched_barrier(0);                                         \
    if (last_) {                                                               \
      asm volatile("s_waitcnt vmcnt(0)" ::: "memory");                         \
    } else if (wave < 3) {                                                     \
      asm volatile("s_waitcnt vmcnt(3)" ::: "memory");                         \
    } else {                                                                   \
      asm volatile("s_waitcnt vmcnt(2)" ::: "memory");                         \
    }                                                                          \
    __builtin_amdgcn_sched_barrier(0);                                         \
    __builtin_amdgcn_s_barrier();                                              \
    if (dostage_) STAGE((s_) + 2, smem + (NSL)*19456);                         \
    const char* L = smem + (SL)*19456;                                         \
    unsigned long long mb0 = *(const unsigned long long*)(                     \
        L + 18432 + (((rh << 5) + l16) << 4) + (ctw << 3));                    \
    unsigned long long mb1 = *(const unsigned long long*)(                     \
        L + 18432 + (((rh << 5) + 16 + l16) << 4) + (ctw << 3));               \
    H8 ET, ETN;                                                                \
    ET.v = *(const h8*)(L + 16384 + (ctw << 7) + (kfw << 6) + (quad << 4));    \
    ETN.v = *(const h8*)(L + 17408 + (ctw << 7) + (kfw << 6) + (quad << 4));   \
    const char* fB = L + (ctw << 13) + (kfw << 12) + (lane << 4);              \
    h8 B0 = *(const h8*)(fB);                                                  \
    h8 B1 = *(const h8*)(fB + 1024);                                           \
    h8 B2 = *(const h8*)(fB + 2048);                                           \
    h8 B3 = *(const h8*)(fB + 3072);                                           \
    _Pragma("unroll") for (int rt = 0; rt < 2; ++rt) {                         \
      const unsigned byt = (unsigned)((rt ? mb1 : mb0) >> shTot) & 0xFFu;      \
      H4 mlo, mhi;                                                             \
      mlo.v = lutS[byt & 15u];                                                 \
      mhi.v = lutS[byt >> 4];                                                  \
      H8 P;                                                                    \
      _Pragma("unroll") for (int p = 0; p < 4; ++p) {                          \
        h2 a_ = esp[rt] * ET.p[p];                                             \
        h2 b_ = esnp[rt] * ETN.p[p];                                           \
        h2 r_ = __builtin_elementwise_max(a_, b_);                             \
        P.p[p] = r_ * (p < 2 ? mlo.p[p] : mhi.p[p - 2]);                       \
      }                                                                        \
      __builtin_amdgcn_s_setprio(1);                                           \
      acc[rt][0] =                                                             \
          __builtin_amdgcn_mfma_f32_16x16x32_f16(P.v, B0, acc[rt][0], 0, 0, 0);\
      acc[rt][1] =                                                             \
          __builtin_amdgcn_mfma_f32_16x16x32_f16(P.v, B1, acc[rt][1], 0, 0, 0);\
      acc[rt][2] =                                                             \
          __builtin_amdgcn_mfma_f32_16x16x32_f16(P.v, B2, acc[rt][2], 0, 0, 0);\
      acc[rt][3] =                                                             \
          __builtin_amdgcn_mfma_f32_16x16x32_f16(P.v, B3, acc[rt][3], 0, 0, 0);\
      accd[rt] =                                                               \
          __builtin_amdgcn_mfma_f32_16x16x32_f16(P.v, ONES, accd[rt], 0, 0, 0);\
      __builtin_amdgcn_s_setprio(0);                                           \
    }                                                                          \
  }

  // prologue: stage steps 0 and 1
  STAGE(0, smem);
  STAGE(1, smem + 19456);

  for (int sb = 0; sb < 30; sb += 3) {
    ITER(sb + 0, 0, 2, 1, 0);
    ITER(sb + 1, 1, 0, 1, 0);
    ITER(sb + 2, 2, 1, 1, 0);
  }
  ITER(30, 0, 2, 0, 0);
  ITER(31, 1, 0, 0, 1);
#undef ITER
#undef STAGE

  // epilogue: 2 phases (rt); 4-way cross-wave reduce via re-used LDS.
  // accd[rt][r]: every lane holds den(row quad*4+r).
  float(*accL)[16][68] = (float(*)[16][68])smem;   // 34,816 B
  float* denL = (float*)(smem + 8 * 16 * 68 * 4);  // 512 B
  const int erow = tid >> 4;  // 0..31
  const int rh_o = erow >> 4, r16 = erow & 15;
  const int ec0 = (tid & 15) << 2;
#pragma unroll
  for (int rt = 0; rt < 2; ++rt) {
    __syncthreads();
#pragma unroll
    for (int nb = 0; nb < 4; ++nb)
#pragma unroll
      for (int r = 0; r < 4; ++r)
        accL[wave][quad * 4 + r][nb * 16 + l16] = acc[rt][nb][r];
    if (l16 == 0) {
#pragma unroll
      for (int r = 0; r < 4; ++r) denL[wave * 16 + quad * 4 + r] = accd[rt][r];
    }
    __syncthreads();
    f32x4 v = (f32x4){0.f, 0.f, 0.f, 0.f};
    float dn = 0.f;
#pragma unroll
    for (int cw = 0; cw < 4; ++cw) {
      const int w = rh_o + ((cw & 1) << 1) + ((cw >> 1) << 2);
      v += *(const f32x4*)&accL[w][r16][ec0];
      dn += denL[w * 16 + r16];
    }
    float inv = 1.0f / dn;  // self loop -> dn > 0
    const f32x4 bv = *(const f32x4*)(bias + h * FF + ec0);
#pragma unroll
    for (int i = 0; i < 4; ++i) {
      float x = v[i] * inv + bv[i];
      v[i] = x > 0.f ? x : (__expf(x) - 1.0f);
    }
    *(f32x4*)(out + (size_t)(n0 + (rh_o << 5) + (rt << 4) + r16) * (HH * FF) +
              h * FF + ec0) = v;
  }
}

// ---------------------------------------------------------------- launch
extern "C" void kernel_launch(void* const* d_in, const int* in_sizes, int n_in,
                              void* d_out, int out_size, void* d_ws,
                              size_t ws_size, hipStream_t stream) {
  const float* X = (const float*)d_in[0];
  const int* A = (const int*)d_in[1];
  const float* W = (const float*)d_in[2];
  const float* b = (const float*)d_in[3];
  const float* a_self = (const float*)d_in[4];
  const float* a_neigh = (const float*)d_in[5];
  float* out = (float*)d_out;

  char* ws = (char*)d_ws;
  unsigned long long* Abits = (unsigned long long*)ws;        // 2 MB
  _Float16* feats_sw = (_Float16*)(ws + (2u << 20));          // 4 MB
  _Float16* es_h = (_Float16*)(ws + (6u << 20));              // 64 KB each
  _Float16* esn_h = (_Float16*)(ws + (6u << 20) + (64u << 10));
  _Float16* et_h = (_Float16*)(ws + (6u << 20) + (128u << 10));
  _Float16* etn_h = (_Float16*)(ws + (6u << 20) + (192u << 10));
  _Float16* Wsw = (_Float16*)(ws + (6u << 20) + (256u << 10));   // 128 KB
  _Float16* Xsw = (_Float16*)(ws + (6u << 20) + (384u << 10));   // 1 MB

  // K1: swizzle (66) || A-pack rows 0..2047 (2048)
  k1_kernel<<<66 + 2048, 256, 0, stream>>>(A, W, X, Abits, Wsw, Xsw);
  // K2: feats (512, first) || A-pack rows 2048..4095 (2048)
  k2_kernel<<<512 + 2048, 256, 0, stream>>>(A, Abits, Xsw, Wsw, a_self,
                                            a_neigh, feats_sw, es_h, esn_h,
                                            et_h, etn_h);
  // K3: attn — v11 verbatim
  attn_kernel<<<512, 512, 0, stream>>>(Abits, feats_sw, es_h, esn_h, et_h,
                                       etn_h, b, out);
}